// Round 3
// baseline (1089.824 us; speedup 1.0000x reference)
//
#include <hip/hip_runtime.h>
#include <math.h>

// Problem constants
//   B=128, S=256, DIM=512, D=128, K=16384, grid 16x16 -> conv out 8x8 -> N=B*64=8192
#define NROWS 8192
#define KCB   16384

// ---------------------------------------------------------------------------
// k_wt: transpose conv_w [co][ci][kh][kw] -> W2 [(kh*3+kw)][ci][co]  (f32)
__global__ __launch_bounds__(256) void k_wt(const float* __restrict__ cw,
                                            float* __restrict__ W2) {
    int gid = blockIdx.x * 256 + threadIdx.x;     // 147456 total
    if (gid >= 147456) return;
    int co = gid & 127;
    int ci = (gid >> 7) & 127;
    int kk = gid >> 14;                           // 0..8
    W2[gid] = cw[(size_t)co * 1152 + ci * 9 + kk];
}

// ---------------------------------------------------------------------------
// k_c2: c2f[k] = sum_d cb[k][d]^2  (fp64 accum, stored f32)
__global__ __launch_bounds__(256) void k_c2(const float* __restrict__ cb,
                                            float* __restrict__ c2f) {
    int k = blockIdx.x * 256 + threadIdx.x;
    const float* row = cb + (size_t)k * 128;
    double s = 0.0;
    #pragma unroll
    for (int d = 0; d < 128; d += 4) {
        float4 v = *(const float4*)(row + d);
        s += (double)v.x * v.x + (double)v.y * v.y
           + (double)v.z * v.z + (double)v.w * v.w;
    }
    c2f[k] = (float)s;
}

// ---------------------------------------------------------------------------
// k_encode_gemm: H = (last - first) @ W_in   (fp64 accumulate)
//   last/first: [32768, 512] f32, W_in: [512,128] f32, H: [32768,128] double
// biases cancel in the difference (encode is affine, conv is linear).
__global__ __launch_bounds__(256) void k_encode_gemm(
    const float* __restrict__ last, const float* __restrict__ first,
    const float* __restrict__ W_in, double* __restrict__ H)
{
    __shared__ double As[32][64];   // [d][row] (transposed)  16 KiB
    __shared__ float  Bs[32][128];  // [d][col]               16 KiB
    const int tid  = threadIdx.x;
    const int row0 = blockIdx.x * 64;
    const int tx = tid & 31;        // col group: cols tx*4..tx*4+3
    const int ty = tid >> 5;        // row group: rows ty*8..ty*8+7

    double acc[8][4];
    #pragma unroll
    for (int r = 0; r < 8; ++r)
        #pragma unroll
        for (int j = 0; j < 4; ++j) acc[r][j] = 0.0;

    for (int d0 = 0; d0 < 512; d0 += 32) {
        #pragma unroll
        for (int it = 0; it < 2; ++it) {            // stage A-diff transposed
            int flat = it * 1024 + tid * 4;         // 2048 = 64 rows x 32 d
            int r = flat >> 5, d = flat & 31;
            const float4 l4 = *(const float4*)(last  + (size_t)(row0 + r) * 512 + d0 + d);
            const float4 f4 = *(const float4*)(first + (size_t)(row0 + r) * 512 + d0 + d);
            As[d + 0][r] = (double)l4.x - (double)f4.x;
            As[d + 1][r] = (double)l4.y - (double)f4.y;
            As[d + 2][r] = (double)l4.z - (double)f4.z;
            As[d + 3][r] = (double)l4.w - (double)f4.w;
        }
        #pragma unroll
        for (int it = 0; it < 4; ++it) {            // stage B
            int flat = it * 1024 + tid * 4;         // 4096 = 32 d x 128 c
            int d = flat >> 7, c = flat & 127;
            *(float4*)&Bs[d][c] = *(const float4*)(W_in + (size_t)(d0 + d) * 128 + c);
        }
        __syncthreads();
        #pragma unroll 4
        for (int d = 0; d < 32; ++d) {
            double a[8];
            #pragma unroll
            for (int q = 0; q < 4; ++q) {
                double2 t = *(const double2*)&As[d][ty * 8 + 2 * q];
                a[2 * q] = t.x; a[2 * q + 1] = t.y;
            }
            float4 bf = *(const float4*)&Bs[d][tx * 4];
            double b[4] = {(double)bf.x, (double)bf.y, (double)bf.z, (double)bf.w};
            #pragma unroll
            for (int r = 0; r < 8; ++r)
                #pragma unroll
                for (int j = 0; j < 4; ++j)
                    acc[r][j] = fma(a[r], b[j], acc[r][j]);
        }
        __syncthreads();
    }
    #pragma unroll
    for (int r = 0; r < 8; ++r) {
        double* o = H + (size_t)(row0 + ty * 8 + r) * 128 + tx * 4;
        o[0] = acc[r][0]; o[1] = acc[r][1]; o[2] = acc[r][2]; o[3] = acc[r][3];
    }
}

// ---------------------------------------------------------------------------
// k_conv: 3x3 stride-2 pad-1 conv (no bias; cancels), fp64.
//   H viewed as [B][16][16][128] (s-major, ci inner). Out X/Xf: [N=8192][128].
// grid: (b*8 + oh), 256 threads = 2 ow-halves x 128 co.  LDS 48 KiB.
__global__ __launch_bounds__(256) void k_conv(
    const double* __restrict__ H, const float* __restrict__ W2,
    double* __restrict__ X, float* __restrict__ Xf)
{
    __shared__ double Hs[3 * 16 * 128];             // [kh][iw][ci]
    const int b   = blockIdx.x >> 3;
    const int oh  = blockIdx.x & 7;
    const int tid = threadIdx.x;
    const int ih0 = 2 * oh - 1;
    for (int it = 0; it < 24; ++it) {
        int idx = it * 256 + tid;                   // 6144 doubles
        int r = idx >> 11;
        int rem = idx & 2047;
        int ih = ih0 + r;
        Hs[idx] = (ih >= 0) ? H[(size_t)b * 32768 + (size_t)ih * 2048 + rem] : 0.0;
    }
    __syncthreads();
    const int co   = tid & 127;
    const int half = tid >> 7;                      // ow in [half*4, half*4+3]
    const int iwb  = half * 8 - 1;
    double acc[4] = {0, 0, 0, 0};
    for (int ci = 0; ci < 128; ++ci) {
        #pragma unroll
        for (int kh = 0; kh < 3; ++kh) {
            double in[9];
            #pragma unroll
            for (int t = 0; t < 9; ++t) {
                int iw = iwb + t;
                in[t] = (iw >= 0) ? Hs[kh * 2048 + iw * 128 + ci] : 0.0;
            }
            #pragma unroll
            for (int kw = 0; kw < 3; ++kw) {
                double w = (double)W2[(size_t)((kh * 3 + kw) * 128 + ci) * 128 + co];
                #pragma unroll
                for (int i = 0; i < 4; ++i)
                    acc[i] = fma(in[2 * i + kw], w, acc[i]);
            }
        }
    }
    #pragma unroll
    for (int i = 0; i < 4; ++i) {
        int ow = half * 4 + i;
        size_t n = (size_t)b * 64 + oh * 8 + ow;
        X [n * 128 + co] = acc[i];
        Xf[n * 128 + co] = (float)acc[i];
    }
}

// ---------------------------------------------------------------------------
// k_dist: fp32 sweep of s(k) = ||c_k||^2 - 2 x.c_k ; per row keep top-4 per
// K-quarter. 256 threads; block = 64 rows x 4096-k span; grid (128, 4).
// Static LDS exactly 64 KiB (sharedMemPerBlock limit): Xs[128][64]+Cs[128][64].
// Cs columns XOR-swizzled by k ^ ((d>>2)&28): stage-writes 4-way conflicted
// (1.58x on a small fraction), compute reads float4 / broadcast (free).
__global__ __launch_bounds__(256) void k_dist(
    const float* __restrict__ Xf, const float* __restrict__ cb,
    const float* __restrict__ c2f, int* __restrict__ cand)
{
    __shared__ float Xs[128][64];          // [d][row]        32 KiB
    __shared__ float Cs[128][64];          // [d][k^swz]      32 KiB
    const int tid   = threadIdx.x;
    const int row0  = blockIdx.x * 64;
    const int split = blockIdx.y;
    const int kbase0 = split * 4096;
    const int tx = tid & 15;               // k: tx*4 .. tx*4+3 within chunk
    const int ty = tid >> 4;               // rows: ty*4 .. ty*4+3

    #pragma unroll
    for (int it = 0; it < 8; ++it) {       // stage x transposed (once)
        int flat = it * 1024 + tid * 4;    // 8192 = 64 rows x 128 d  (FIXED: 8 its)
        int r = flat >> 7, d = flat & 127;
        float4 v = *(const float4*)(Xf + (size_t)(row0 + r) * 128 + d);
        Xs[d + 0][r] = v.x;
        Xs[d + 1][r] = v.y;
        Xs[d + 2][r] = v.z;
        Xs[d + 3][r] = v.w;
    }

    float v1[4], v2[4]; int i1[4], i2[4];
    #pragma unroll
    for (int r = 0; r < 4; ++r) { v1[r] = v2[r] = 3.0e38f; i1[r] = i2[r] = 0; }

    for (int chunk = 0; chunk < 64; ++chunk) {
        int kb = kbase0 + chunk * 64;
        __syncthreads();
        #pragma unroll
        for (int it = 0; it < 8; ++it) {   // stage codebook chunk (64k x 128d)
            int flat = it * 1024 + tid * 4;
            int kk = flat >> 7, d = flat & 127;
            float4 v = *(const float4*)(cb + (size_t)(kb + kk) * 128 + d);
            int sw = (d >> 2) & 28;        // same for d..d+3 (d multiple of 4)
            int kc = kk ^ sw;
            Cs[d + 0][kc] = v.x;
            Cs[d + 1][kc] = v.y;
            Cs[d + 2][kc] = v.z;
            Cs[d + 3][kc] = v.w;
        }
        __syncthreads();

        float acc[4][4];
        #pragma unroll
        for (int r = 0; r < 4; ++r)
            #pragma unroll
            for (int j = 0; j < 4; ++j) acc[r][j] = 0.f;

        #pragma unroll 4
        for (int d = 0; d < 128; ++d) {
            float4 a4 = *(const float4*)&Xs[d][ty * 4];
            int sw = (d >> 2) & 28;
            float4 b4 = *(const float4*)&Cs[d][(tx * 4) ^ sw];
            float a[4] = {a4.x, a4.y, a4.z, a4.w};
            float bb[4] = {b4.x, b4.y, b4.z, b4.w};
            #pragma unroll
            for (int r = 0; r < 4; ++r)
                #pragma unroll
                for (int j = 0; j < 4; ++j)
                    acc[r][j] = fmaf(a[r], bb[j], acc[r][j]);
        }
        #pragma unroll
        for (int j = 0; j < 4; ++j) {
            int kg = kb + tx * 4 + j;
            float c2v = c2f[kg];           // L1-resident (64 KiB total)
            #pragma unroll
            for (int r = 0; r < 4; ++r) {
                float s = fmaf(-2.f, acc[r][j], c2v);
                if (s < v1[r]) { v2[r] = v1[r]; i2[r] = i1[r]; v1[r] = s; i1[r] = kg; }
                else if (s < v2[r]) { v2[r] = s; i2[r] = kg; }
            }
        }
    }

    // block reduce: per row, top-4 of 16 threads x 2 candidates (reuse Cs)
    __syncthreads();
    float* dv = &Cs[0][0];                 // [64 rows][32]
    int*   di = (int*)&Cs[32][0];          // [64 rows][32]
    #pragma unroll
    for (int r = 0; r < 4; ++r) {
        int row = ty * 4 + r;
        dv[row * 32 + tx * 2]     = v1[r];  di[row * 32 + tx * 2]     = i1[r];
        dv[row * 32 + tx * 2 + 1] = v2[r];  di[row * 32 + tx * 2 + 1] = i2[r];
    }
    __syncthreads();
    if (tid < 64) {
        int row = tid;
        float bv[4] = {3e38f, 3e38f, 3e38f, 3e38f};
        int   bi[4] = {0, 0, 0, 0};
        for (int e = 0; e < 32; ++e) {
            float v = dv[row * 32 + e]; int ix = di[row * 32 + e];
            if (v < bv[3]) {
                bv[3] = v; bi[3] = ix;
                #pragma unroll
                for (int p = 3; p > 0; --p) {
                    if (bv[p] < bv[p - 1]) {
                        float tv = bv[p]; bv[p] = bv[p - 1]; bv[p - 1] = tv;
                        int   ti = bi[p]; bi[p] = bi[p - 1]; bi[p - 1] = ti;
                    }
                }
            }
        }
        int* o = cand + (size_t)(row0 + row) * 16 + split * 4;
        o[0] = bi[0]; o[1] = bi[1]; o[2] = bi[2]; o[3] = bi[3];
    }
}

// ---------------------------------------------------------------------------
// k_refine: fp64-exact argmin over 16 candidates; quantize; counts; indices.
// 1 wave per row. Candidate index clamped — a bad candidate can never fault.
__global__ __launch_bounds__(256) void k_refine(
    const double* __restrict__ X, const float* __restrict__ cb,
    const int* __restrict__ cand, const float* __restrict__ rnd,
    int* __restrict__ counts, float* __restrict__ quant,
    float* __restrict__ out_mi)
{
    const int wid  = threadIdx.x >> 6;
    const int lane = threadIdx.x & 63;
    const int row  = blockIdx.x * 4 + wid;
    const double x0 = X[(size_t)row * 128 + lane];
    const double x1 = X[(size_t)row * 128 + 64 + lane];
    double bestv = 1e300; int bestk = 0;
    for (int c = 0; c < 16; ++c) {
        int k = cand[(size_t)row * 16 + c] & (KCB - 1);   // defensive clamp
        double t0 = x0 - (double)cb[(size_t)k * 128 + lane];
        double t1 = x1 - (double)cb[(size_t)k * 128 + 64 + lane];
        double s = t0 * t0 + t1 * t1;
        #pragma unroll
        for (int off = 32; off > 0; off >>= 1) s += __shfl_xor(s, off, 64);
        if (s < bestv) { bestv = s; bestk = k; }
    }
    double r0 = (double)rnd[(size_t)row * 128 + lane];
    double r1 = (double)rnd[(size_t)row * 128 + 64 + lane];
    double rs = r0 * r0 + r1 * r1;
    #pragma unroll
    for (int off = 32; off > 0; off >>= 1) rs += __shfl_xor(rs, off, 64);
    double ratio = sqrt(bestv) / sqrt(rs) + 1e-12;
    quant[(size_t)row * 128 + lane]      = (float)(x0 + ratio * r0);
    quant[(size_t)row * 128 + 64 + lane] = (float)(x1 + ratio * r1);
    if (lane == 0) {
        out_mi[row] = (float)bestk;
        atomicAdd(counts + bestk, 1);
    }
}

// ---------------------------------------------------------------------------
// k_perplex: perplexity + new_used (single block)
__global__ __launch_bounds__(256) void k_perplex(
    const int* __restrict__ counts, const int* __restrict__ used_in,
    float* __restrict__ out_used, float* __restrict__ out_perp)
{
    __shared__ double red[256];
    int tid = threadIdx.x;
    double e = 0.0;
    for (int k = tid; k < KCB; k += 256) {
        int c = counts[k];
        out_used[k] = (float)(used_in[k] + c);
        if (c > 0) {
            double p = (double)c / 8192.0;
            e += p * log(p + 1e-12);
        }
    }
    red[tid] = e;
    __syncthreads();
    for (int s = 128; s > 0; s >>= 1) {
        if (tid < s) red[tid] += red[tid + s];
        __syncthreads();
    }
    if (tid == 0) out_perp[0] = (float)exp(-red[0]);
}

// ---------------------------------------------------------------------------
// k_decode: out[b,s2,m] = sum_d2 quantflat[b*8192 + d2*64 + s2] * W_out[d2,m] + b_out[m]
// grid (8 m-tiles, 128 b), 256 threads, micro 4x4.  LDS 64 KiB.
__global__ __launch_bounds__(256) void k_decode(
    const float* __restrict__ quant, const float* __restrict__ W_out,
    const float* __restrict__ b_out, float* __restrict__ out)
{
    __shared__ float As[8192];             // [d2][s2] (raw reinterpretation!)
    __shared__ float Bs[8192];             // [d2][64 m]
    const int tid = threadIdx.x;
    const int m0  = blockIdx.x * 64;
    const int b   = blockIdx.y;
    #pragma unroll
    for (int it = 0; it < 8; ++it) {
        int flat = it * 1024 + tid * 4;
        *(float4*)&As[flat] = *(const float4*)(quant + (size_t)b * 8192 + flat);
        int d2 = flat >> 6, m = flat & 63;
        *(float4*)&Bs[flat] = *(const float4*)(W_out + (size_t)d2 * 512 + m0 + m);
    }
    __syncthreads();
    const int tx = tid & 15, ty = tid >> 4;
    float acc[4][4];
    #pragma unroll
    for (int i = 0; i < 4; ++i)
        #pragma unroll
        for (int j = 0; j < 4; ++j) acc[i][j] = 0.f;
    #pragma unroll 8
    for (int d2 = 0; d2 < 128; ++d2) {
        float4 a  = *(const float4*)&As[d2 * 64 + ty * 4];
        float4 b4 = *(const float4*)&Bs[d2 * 64 + tx * 4];
        float av[4] = {a.x, a.y, a.z, a.w};
        float bv[4] = {b4.x, b4.y, b4.z, b4.w};
        #pragma unroll
        for (int i = 0; i < 4; ++i)
            #pragma unroll
            for (int j = 0; j < 4; ++j)
                acc[i][j] = fmaf(av[i], bv[j], acc[i][j]);
    }
    float4 bo = *(const float4*)(b_out + m0 + tx * 4);
    float bob[4] = {bo.x, bo.y, bo.z, bo.w};
    #pragma unroll
    for (int i = 0; i < 4; ++i) {
        int s2 = ty * 4 + i;
        float4 o;
        o.x = acc[i][0] + bob[0];
        o.y = acc[i][1] + bob[1];
        o.z = acc[i][2] + bob[2];
        o.w = acc[i][3] + bob[3];
        *(float4*)(out + (size_t)b * 32768 + (size_t)s2 * 512 + m0 + tx * 4) = o;
    }
}

// ---------------------------------------------------------------------------
extern "C" void kernel_launch(void* const* d_in, const int* in_sizes, int n_in,
                              void* d_out, int out_size, void* d_ws, size_t ws_size,
                              hipStream_t stream) {
    const float* first  = (const float*)d_in[0];
    const float* last   = (const float*)d_in[1];
    const float* rnd    = (const float*)d_in[2];
    const float* cb     = (const float*)d_in[3];
    const float* W_in   = (const float*)d_in[4];
    const float* conv_w = (const float*)d_in[6];
    const float* W_out  = (const float*)d_in[8];
    const float* b_out  = (const float*)d_in[9];
    const int*   used   = (const int*)d_in[10];

    float* out      = (float*)d_out;
    float* out_perp = out + 4194304;               // B*64*DIM
    float* out_used = out + 4194305;
    float* out_mi   = out + 4194305 + 16384;

    char* ws = (char*)d_ws;
    double* H     = (double*)(ws);                 // 33,554,432 B
    double* X     = (double*)(ws + 33554432);      //  8,388,608 B
    float*  Xf    = (float*) (ws + 41943040);      //  4,194,304 B
    float*  W2    = (float*) (ws + 46137344);      //    589,824 B
    float*  c2f   = (float*) (ws + 46727168);      //     65,536 B
    int*    cand  = (int*)   (ws + 46792704);      //    524,288 B
    float*  quant = (float*) (ws + 47316992);      //  4,194,304 B
    int*    counts= (int*)   (ws + 51511296);      //     65,536 B

    hipMemsetAsync(counts, 0, KCB * sizeof(int), stream);
    k_wt<<<576, 256, 0, stream>>>(conv_w, W2);
    k_c2<<<64, 256, 0, stream>>>(cb, c2f);
    k_encode_gemm<<<512, 256, 0, stream>>>(last, first, W_in, H);
    k_conv<<<1024, 256, 0, stream>>>(H, W2, X, Xf);
    k_dist<<<dim3(128, 4), 256, 0, stream>>>(Xf, cb, c2f, cand);
    k_refine<<<2048, 256, 0, stream>>>(X, cb, cand, rnd, counts, quant, out_mi);
    k_perplex<<<1, 256, 0, stream>>>(counts, used, out_used, out_perp);
    k_decode<<<dim3(8, 128), 256, 0, stream>>>(quant, W_out, b_out, out);
}

// Round 4
// 530.923 us; speedup vs baseline: 2.0527x; 2.0527x over previous
//
#include <hip/hip_runtime.h>
#include <math.h>

// Problem constants
//   B=128, S=256, DIM=512, D=128, K=16384, grid 16x16 -> conv out 8x8 -> N=B*64=8192
#define NROWS 8192
#define KCB   16384

using frag_ab = __attribute__((ext_vector_type(8))) short;   // 8 bf16 (4 VGPR)
using frag_cd = __attribute__((ext_vector_type(4))) float;   // 4 fp32 acc
using f32x4   = __attribute__((ext_vector_type(4))) float;

__device__ inline unsigned short f2bf(float f) {             // RNE f32->bf16
    unsigned u = __float_as_uint(f);
    return (unsigned short)((u + 0x7FFFu + ((u >> 16) & 1u)) >> 16);
}

// ---------------------------------------------------------------------------
// k_wt: transpose conv_w [co][ci][kh][kw] -> W2 [(kh*3+kw)][ci][co]  (f32)
__global__ __launch_bounds__(256) void k_wt(const float* __restrict__ cw,
                                            float* __restrict__ W2) {
    int gid = blockIdx.x * 256 + threadIdx.x;     // 147456 total
    if (gid >= 147456) return;
    int co = gid & 127;
    int ci = (gid >> 7) & 127;
    int kk = gid >> 14;                           // 0..8
    W2[gid] = cw[(size_t)co * 1152 + ci * 9 + kk];
}

// ---------------------------------------------------------------------------
// k_c2: c2f[k] = sum_d cb[k][d]^2 + 1024  (bias keeps k_dist scores positive
// so raw float bits are a monotone sort key; k_refine never reads c2f)
__global__ __launch_bounds__(256) void k_c2(const float* __restrict__ cb,
                                            float* __restrict__ c2f) {
    int k = blockIdx.x * 256 + threadIdx.x;
    const float* row = cb + (size_t)k * 128;
    double s = 0.0;
    #pragma unroll
    for (int d = 0; d < 128; d += 4) {
        float4 v = *(const float4*)(row + d);
        s += (double)v.x * v.x + (double)v.y * v.y
           + (double)v.z * v.z + (double)v.w * v.w;
    }
    c2f[k] = (float)s + 1024.0f;
}

// ---------------------------------------------------------------------------
// k_cbbf: convert codebook f32 -> bf16 rows [16384][128]
__global__ __launch_bounds__(256) void k_cbbf(const float* __restrict__ cb,
                                              unsigned short* __restrict__ Cbb) {
    int gid = blockIdx.x * 256 + threadIdx.x;     // x4 elements, 524288 total
    float4 v = ((const float4*)cb)[gid];
    ushort4 o;
    o.x = f2bf(v.x); o.y = f2bf(v.y); o.z = f2bf(v.z); o.w = f2bf(v.w);
    ((ushort4*)Cbb)[gid] = o;
}

// ---------------------------------------------------------------------------
// k_encode_gemm: H = (last - first) @ W_in   (fp64 accumulate)
__global__ __launch_bounds__(256) void k_encode_gemm(
    const float* __restrict__ last, const float* __restrict__ first,
    const float* __restrict__ W_in, double* __restrict__ H)
{
    __shared__ double As[32][64];   // [d][row] (transposed)  16 KiB
    __shared__ float  Bs[32][128];  // [d][col]               16 KiB
    const int tid  = threadIdx.x;
    const int row0 = blockIdx.x * 64;
    const int tx = tid & 31;        // col group: cols tx*4..tx*4+3
    const int ty = tid >> 5;        // row group: rows ty*8..ty*8+7

    double acc[8][4];
    #pragma unroll
    for (int r = 0; r < 8; ++r)
        #pragma unroll
        for (int j = 0; j < 4; ++j) acc[r][j] = 0.0;

    for (int d0 = 0; d0 < 512; d0 += 32) {
        #pragma unroll
        for (int it = 0; it < 2; ++it) {            // stage A-diff transposed
            int flat = it * 1024 + tid * 4;         // 2048 = 64 rows x 32 d
            int r = flat >> 5, d = flat & 31;
            const float4 l4 = *(const float4*)(last  + (size_t)(row0 + r) * 512 + d0 + d);
            const float4 f4 = *(const float4*)(first + (size_t)(row0 + r) * 512 + d0 + d);
            As[d + 0][r] = (double)l4.x - (double)f4.x;
            As[d + 1][r] = (double)l4.y - (double)f4.y;
            As[d + 2][r] = (double)l4.z - (double)f4.z;
            As[d + 3][r] = (double)l4.w - (double)f4.w;
        }
        #pragma unroll
        for (int it = 0; it < 4; ++it) {            // stage B
            int flat = it * 1024 + tid * 4;         // 4096 = 32 d x 128 c
            int d = flat >> 7, c = flat & 127;
            *(float4*)&Bs[d][c] = *(const float4*)(W_in + (size_t)(d0 + d) * 128 + c);
        }
        __syncthreads();
        #pragma unroll 4
        for (int d = 0; d < 32; ++d) {
            double a[8];
            #pragma unroll
            for (int q = 0; q < 4; ++q) {
                double2 t = *(const double2*)&As[d][ty * 8 + 2 * q];
                a[2 * q] = t.x; a[2 * q + 1] = t.y;
            }
            float4 bf = *(const float4*)&Bs[d][tx * 4];
            double b[4] = {(double)bf.x, (double)bf.y, (double)bf.z, (double)bf.w};
            #pragma unroll
            for (int r = 0; r < 8; ++r)
                #pragma unroll
                for (int j = 0; j < 4; ++j)
                    acc[r][j] = fma(a[r], b[j], acc[r][j]);
        }
        __syncthreads();
    }
    #pragma unroll
    for (int r = 0; r < 8; ++r) {
        double* o = H + (size_t)(row0 + ty * 8 + r) * 128 + tx * 4;
        o[0] = acc[r][0]; o[1] = acc[r][1]; o[2] = acc[r][2]; o[3] = acc[r][3];
    }
}

// ---------------------------------------------------------------------------
// k_conv: 3x3 stride-2 pad-1 conv (no bias; cancels), fp64.
// Writes X (f64, for refine/quantize) and Xb (bf16, for MFMA candidate sweep).
__global__ __launch_bounds__(256) void k_conv(
    const double* __restrict__ H, const float* __restrict__ W2,
    double* __restrict__ X, unsigned short* __restrict__ Xb)
{
    __shared__ double Hs[3 * 16 * 128];             // [kh][iw][ci]  48 KiB
    const int b   = blockIdx.x >> 3;
    const int oh  = blockIdx.x & 7;
    const int tid = threadIdx.x;
    const int ih0 = 2 * oh - 1;
    for (int it = 0; it < 24; ++it) {
        int idx = it * 256 + tid;                   // 6144 doubles
        int r = idx >> 11;
        int rem = idx & 2047;
        int ih = ih0 + r;
        Hs[idx] = (ih >= 0) ? H[(size_t)b * 32768 + (size_t)ih * 2048 + rem] : 0.0;
    }
    __syncthreads();
    const int co   = tid & 127;
    const int half = tid >> 7;                      // ow in [half*4, half*4+3]
    const int iwb  = half * 8 - 1;
    double acc[4] = {0, 0, 0, 0};
    for (int ci = 0; ci < 128; ++ci) {
        #pragma unroll
        for (int kh = 0; kh < 3; ++kh) {
            double in[9];
            #pragma unroll
            for (int t = 0; t < 9; ++t) {
                int iw = iwb + t;
                in[t] = (iw >= 0) ? Hs[kh * 2048 + iw * 128 + ci] : 0.0;
            }
            #pragma unroll
            for (int kw = 0; kw < 3; ++kw) {
                double w = (double)W2[(size_t)((kh * 3 + kw) * 128 + ci) * 128 + co];
                #pragma unroll
                for (int i = 0; i < 4; ++i)
                    acc[i] = fma(in[2 * i + kw], w, acc[i]);
            }
        }
    }
    #pragma unroll
    for (int i = 0; i < 4; ++i) {
        int ow = half * 4 + i;
        size_t n = (size_t)b * 64 + oh * 8 + ow;
        X [n * 128 + co] = acc[i];
        Xb[n * 128 + co] = f2bf((float)acc[i]);
    }
}

// ---------------------------------------------------------------------------
// k_dist_mfma: bf16 MFMA candidate sweep. Block = 128 rows x 2048-code split;
// grid (64, 8) = 512 blocks (2/CU). Per chunk of 128 codes: 16x16x32 MFMA,
// codes as M, rows as N (D: col=lane&15=row, row=quad*4+reg=code).
// LDS exactly 64 KiB; 16B chunks XOR-swizzled (ch ^= row&15) -> conflict-free.
// Selection: score u = (||c||^2+1024) - 2 x.c > 0; sortable uint key =
// (bits(u) & ~0x7FF) | split-local code idx (11 bits); top-2 per (lane,row)
// class via min/max (no cndmask), then per-row top-2 of 16 via LDS.
// Coverage: bf16 noise sigma~0.05 + trunc <0.5 vs rank gaps ~7-20 -> safe;
// fp64 k_refine picks the exact argmin among the 16 candidates.
__global__ __launch_bounds__(256) void k_dist_mfma(
    const unsigned short* __restrict__ Xb, const unsigned short* __restrict__ Cbb,
    const float* __restrict__ c2f, int* __restrict__ cand)
{
    __shared__ __align__(16) unsigned short Xs[128 * 128];   // 32 KiB
    __shared__ __align__(16) unsigned short Cs[128 * 128];   // 32 KiB
    const int tid   = threadIdx.x;
    const int row0  = blockIdx.x * 128;
    const int split = blockIdx.y;
    const int lane  = tid & 63;
    const int w     = tid >> 6;
    const int quad  = lane >> 4;
    const int lm    = lane & 15;
    const int cw    = (w & 1) * 64;       // wave's code sub-tile
    const int rw    = (w >> 1) * 64;      // wave's row sub-tile

    #pragma unroll
    for (int it = 0; it < 8; ++it) {      // stage X tile once (swizzled)
        int flat = it * 256 + tid;
        int r = flat >> 4, ch = flat & 15;
        *(uint4*)&Xs[r * 128 + (((ch ^ r) & 15) << 3) + (ch & 16 ? 0 : 0)] =
            *(const uint4*)(Xb + (size_t)(row0 + r) * 128 + ch * 8);
    }

    unsigned k1[4], k2[4];
    #pragma unroll
    for (int j = 0; j < 4; ++j) { k1[j] = 0xFFFFFFFFu; k2[j] = 0xFFFFFFFFu; }

    for (int chunk = 0; chunk < 16; ++chunk) {
        const int kb = split * 2048 + chunk * 128;
        if (chunk) __syncthreads();
        #pragma unroll
        for (int it = 0; it < 8; ++it) {  // stage code chunk (swizzled)
            int flat = it * 256 + tid;
            int r = flat >> 4, ch = flat & 15;
            *(uint4*)&Cs[r * 128 + ((ch ^ (r & 15)) << 3)] =
                *(const uint4*)(Cbb + (size_t)(kb + r) * 128 + ch * 8);
        }
        __syncthreads();

        frag_cd acc[4][4];
        #pragma unroll
        for (int i = 0; i < 4; ++i)
            #pragma unroll
            for (int j = 0; j < 4; ++j)
                #pragma unroll
                for (int r = 0; r < 4; ++r) acc[i][j][r] = 0.f;

        #pragma unroll
        for (int kk = 0; kk < 4; ++kk) {
            const int chs = ((kk * 4 + quad) ^ lm) << 3;
            frag_ab a[4], b[4];
            #pragma unroll
            for (int i = 0; i < 4; ++i)
                a[i] = *(const frag_ab*)&Cs[(cw + i * 16 + lm) * 128 + chs];
            #pragma unroll
            for (int j = 0; j < 4; ++j)
                b[j] = *(const frag_ab*)&Xs[(rw + j * 16 + lm) * 128 + chs];
            #pragma unroll
            for (int i = 0; i < 4; ++i)
                #pragma unroll
                for (int j = 0; j < 4; ++j)
                    acc[i][j] = __builtin_amdgcn_mfma_f32_16x16x32_bf16(
                        a[i], b[j], acc[i][j], 0, 0, 0);
        }

        const int ib = chunk * 128 + cw + quad * 4;   // split-local idx base
        #pragma unroll
        for (int i = 0; i < 4; ++i) {
            f32x4 c2v = *(const f32x4*)(c2f + kb + cw + i * 16 + quad * 4);
            #pragma unroll
            for (int j = 0; j < 4; ++j) {
                #pragma unroll
                for (int r = 0; r < 4; ++r) {
                    float u = fmaf(-2.f, acc[i][j][r], c2v[r]);
                    unsigned key = (__float_as_uint(u) & 0xFFFFF800u)
                                 | (unsigned)(ib + i * 16 + r);
                    unsigned nk1 = min(key, k1[j]);
                    k2[j] = min(max(key, k1[j]), k2[j]);
                    k1[j] = nk1;
                }
            }
        }
    }

    // per-row reduce: 8 slots x 2 keys -> top-2 of the split
    __syncthreads();
    uint2* kred = (uint2*)Cs;             // [128 rows][8 slots]
    #pragma unroll
    for (int j = 0; j < 4; ++j)
        kred[(rw + j * 16 + lm) * 8 + (w & 1) * 4 + quad] = make_uint2(k1[j], k2[j]);
    __syncthreads();
    if (tid < 128) {
        unsigned b1 = 0xFFFFFFFFu, b2 = 0xFFFFFFFFu;
        for (int e = 0; e < 8; ++e) {
            uint2 kv = kred[tid * 8 + e];
            unsigned n1 = min(kv.x, b1); b2 = min(max(kv.x, b1), b2); b1 = n1;
            n1 = min(kv.y, b1);          b2 = min(max(kv.y, b1), b2); b1 = n1;
        }
        int base = split * 2048;
        int* o = cand + (size_t)(row0 + tid) * 16 + split * 2;
        o[0] = base + (int)(b1 & 0x7FFu);
        o[1] = base + (int)(b2 & 0x7FFu);
    }
}

// ---------------------------------------------------------------------------
// k_refine: fp64-exact argmin over 16 candidates; quantize; counts; indices.
__global__ __launch_bounds__(256) void k_refine(
    const double* __restrict__ X, const float* __restrict__ cb,
    const int* __restrict__ cand, const float* __restrict__ rnd,
    int* __restrict__ counts, float* __restrict__ quant,
    float* __restrict__ out_mi)
{
    const int wid  = threadIdx.x >> 6;
    const int lane = threadIdx.x & 63;
    const int row  = blockIdx.x * 4 + wid;
    const double x0 = X[(size_t)row * 128 + lane];
    const double x1 = X[(size_t)row * 128 + 64 + lane];
    double bestv = 1e300; int bestk = 0;
    for (int c = 0; c < 16; ++c) {
        int k = cand[(size_t)row * 16 + c] & (KCB - 1);   // defensive clamp
        double t0 = x0 - (double)cb[(size_t)k * 128 + lane];
        double t1 = x1 - (double)cb[(size_t)k * 128 + 64 + lane];
        double s = t0 * t0 + t1 * t1;
        #pragma unroll
        for (int off = 32; off > 0; off >>= 1) s += __shfl_xor(s, off, 64);
        if (s < bestv) { bestv = s; bestk = k; }
    }
    double r0 = (double)rnd[(size_t)row * 128 + lane];
    double r1 = (double)rnd[(size_t)row * 128 + 64 + lane];
    double rs = r0 * r0 + r1 * r1;
    #pragma unroll
    for (int off = 32; off > 0; off >>= 1) rs += __shfl_xor(rs, off, 64);
    double ratio = sqrt(bestv) / sqrt(rs) + 1e-12;
    quant[(size_t)row * 128 + lane]      = (float)(x0 + ratio * r0);
    quant[(size_t)row * 128 + 64 + lane] = (float)(x1 + ratio * r1);
    if (lane == 0) {
        out_mi[row] = (float)bestk;
        atomicAdd(counts + bestk, 1);
    }
}

// ---------------------------------------------------------------------------
// k_perplex: perplexity + new_used (single block)
__global__ __launch_bounds__(256) void k_perplex(
    const int* __restrict__ counts, const int* __restrict__ used_in,
    float* __restrict__ out_used, float* __restrict__ out_perp)
{
    __shared__ double red[256];
    int tid = threadIdx.x;
    double e = 0.0;
    for (int k = tid; k < KCB; k += 256) {
        int c = counts[k];
        out_used[k] = (float)(used_in[k] + c);
        if (c > 0) {
            double p = (double)c / 8192.0;
            e += p * log(p + 1e-12);
        }
    }
    red[tid] = e;
    __syncthreads();
    for (int s = 128; s > 0; s >>= 1) {
        if (tid < s) red[tid] += red[tid + s];
        __syncthreads();
    }
    if (tid == 0) out_perp[0] = (float)exp(-red[0]);
}

// ---------------------------------------------------------------------------
// k_decode: out[b,s2,m] = sum_d2 quant[b*8192 + d2*64 + s2] * W_out[d2,m] + b_out[m]
__global__ __launch_bounds__(256) void k_decode(
    const float* __restrict__ quant, const float* __restrict__ W_out,
    const float* __restrict__ b_out, float* __restrict__ out)
{
    __shared__ float As[8192];             // [d2][s2] (raw reinterpretation!)
    __shared__ float Bs[8192];             // [d2][64 m]
    const int tid = threadIdx.x;
    const int m0  = blockIdx.x * 64;
    const int b   = blockIdx.y;
    #pragma unroll
    for (int it = 0; it < 8; ++it) {
        int flat = it * 1024 + tid * 4;
        *(float4*)&As[flat] = *(const float4*)(quant + (size_t)b * 8192 + flat);
        int d2 = flat >> 6, m = flat & 63;
        *(float4*)&Bs[flat] = *(const float4*)(W_out + (size_t)d2 * 512 + m0 + m);
    }
    __syncthreads();
    const int tx = tid & 15, ty = tid >> 4;
    float acc[4][4];
    #pragma unroll
    for (int i = 0; i < 4; ++i)
        #pragma unroll
        for (int j = 0; j < 4; ++j) acc[i][j] = 0.f;
    #pragma unroll 8
    for (int d2 = 0; d2 < 128; ++d2) {
        float4 a  = *(const float4*)&As[d2 * 64 + ty * 4];
        float4 b4 = *(const float4*)&Bs[d2 * 64 + tx * 4];
        float av[4] = {a.x, a.y, a.z, a.w};
        float bv[4] = {b4.x, b4.y, b4.z, b4.w};
        #pragma unroll
        for (int i = 0; i < 4; ++i)
            #pragma unroll
            for (int j = 0; j < 4; ++j)
                acc[i][j] = fmaf(av[i], bv[j], acc[i][j]);
    }
    float4 bo = *(const float4*)(b_out + m0 + tx * 4);
    float bob[4] = {bo.x, bo.y, bo.z, bo.w};
    #pragma unroll
    for (int i = 0; i < 4; ++i) {
        int s2 = ty * 4 + i;
        float4 o;
        o.x = acc[i][0] + bob[0];
        o.y = acc[i][1] + bob[1];
        o.z = acc[i][2] + bob[2];
        o.w = acc[i][3] + bob[3];
        *(float4*)(out + (size_t)b * 32768 + (size_t)s2 * 512 + m0 + tx * 4) = o;
    }
}

// ---------------------------------------------------------------------------
extern "C" void kernel_launch(void* const* d_in, const int* in_sizes, int n_in,
                              void* d_out, int out_size, void* d_ws, size_t ws_size,
                              hipStream_t stream) {
    const float* first  = (const float*)d_in[0];
    const float* last   = (const float*)d_in[1];
    const float* rnd    = (const float*)d_in[2];
    const float* cb     = (const float*)d_in[3];
    const float* W_in   = (const float*)d_in[4];
    const float* conv_w = (const float*)d_in[6];
    const float* W_out  = (const float*)d_in[8];
    const float* b_out  = (const float*)d_in[9];
    const int*   used   = (const int*)d_in[10];

    float* out      = (float*)d_out;
    float* out_perp = out + 4194304;               // B*64*DIM
    float* out_used = out + 4194305;
    float* out_mi   = out + 4194305 + 16384;

    char* ws = (char*)d_ws;
    double*         H      = (double*)(ws);                 // 33,554,432 B
    double*         X      = (double*)(ws + 33554432);      //  8,388,608 B
    unsigned short* Cbb    = (unsigned short*)(ws + 41943040); // 4,194,304 B
    float*          W2     = (float*) (ws + 46137344);      //    589,824 B
    float*          c2f    = (float*) (ws + 46727168);      //     65,536 B
    int*            cand   = (int*)   (ws + 46792704);      //    524,288 B
    float*          quant  = (float*) (ws + 47316992);      //  4,194,304 B
    int*            counts = (int*)   (ws + 51511296);      //     65,536 B
    unsigned short* Xb     = (unsigned short*)(ws + 51576832); // 2,097,152 B
                                                            // total 53,673,984 B

    hipMemsetAsync(counts, 0, KCB * sizeof(int), stream);
    k_wt<<<576, 256, 0, stream>>>(conv_w, W2);
    k_c2<<<64, 256, 0, stream>>>(cb, c2f);
    k_cbbf<<<2048, 256, 0, stream>>>(cb, Cbb);
    k_encode_gemm<<<512, 256, 0, stream>>>(last, first, W_in, H);
    k_conv<<<1024, 256, 0, stream>>>(H, W2, X, Xb);
    k_dist_mfma<<<dim3(64, 8), 256, 0, stream>>>(Xb, Cbb, c2f, cand);
    k_refine<<<2048, 256, 0, stream>>>(X, cb, cand, rnd, counts, quant, out_mi);
    k_perplex<<<1, 256, 0, stream>>>(counts, used, out_used, out_perp);
    k_decode<<<dim3(8, 128), 256, 0, stream>>>(quant, W_out, b_out, out);
}